// Round 1
// baseline (1635.718 us; speedup 1.0000x reference)
//
#include <hip/hip_runtime.h>

// GCN layer: h = x @ W^T + b  [16384,128];  out = A_hat @ h  [16384,128]
// Strategy: bf16 MFMA for both GEMMs (no fp32 MFMA on CDNA4), in-register
// fp32->bf16 conversion, h stored TRANSPOSED (hT[o][n] bf16) in d_ws so both
// GEMMs have K-contiguous operands -> LDS-free, barrier-free streaming loops.

#define N_NODES 16384
#define IN_DIM  256
#define OUT_DIM 128

typedef short bf16x8 __attribute__((ext_vector_type(8)));
typedef float f32x4  __attribute__((ext_vector_type(4)));

// fp32 -> bf16 bits, round-to-nearest-even (3 VALU ops; inputs are finite)
__device__ __forceinline__ unsigned short f2bf(float f) {
    unsigned u = __float_as_uint(f);
    u += 0x7fffu + ((u >> 16) & 1u);
    return (unsigned short)(u >> 16);
}

// load 8 consecutive fp32 (two dwordx4) and convert to a bf16x8 fragment
__device__ __forceinline__ bf16x8 load_cvt8(const float* __restrict__ p) {
    f32x4 a = *reinterpret_cast<const f32x4*>(p);
    f32x4 c = *reinterpret_cast<const f32x4*>(p + 4);
    bf16x8 r;
#pragma unroll
    for (int i = 0; i < 4; ++i) {
        r[i]     = (short)f2bf(a[i]);
        r[i + 4] = (short)f2bf(c[i]);
    }
    return r;
}

// ---------------------------------------------------------------------------
// GEMM1: hT[o][n] = sum_k W[o][k] * x[n][k] + b[o]      (M=128 o, N=16384 n, K=256)
// Block: 256 thr = 4 waves (2x2), tile 128(o) x 128(n); wave tile 64x64
// (4x4 frags of 16x16x32). Grid = 16384/128 = 128 blocks.
// ---------------------------------------------------------------------------
__global__ __launch_bounds__(256) void gemm1_xw(
    const float* __restrict__ x, const float* __restrict__ W,
    const float* __restrict__ b, unsigned short* __restrict__ hT) {
    const int tid  = threadIdx.x;
    const int lane = tid & 63, wid = tid >> 6;
    const int l16  = lane & 15, quad = lane >> 4;
    const int n0   = blockIdx.x * 128;
    const int wm   = (wid >> 1) * 64;   // o-offset of wave
    const int wn   = (wid & 1) * 64;    // n-offset of wave

    f32x4 acc[4][4] = {};

    const float* aBase = W + (size_t)(wm + l16) * IN_DIM + quad * 8;
    const float* bBase = x + (size_t)(n0 + wn + l16) * IN_DIM + quad * 8;

#pragma unroll 2
    for (int k = 0; k < IN_DIM; k += 32) {
        bf16x8 af[4], bfr[4];
#pragma unroll
        for (int mf = 0; mf < 4; ++mf)
            af[mf] = load_cvt8(aBase + (size_t)mf * 16 * IN_DIM + k);
#pragma unroll
        for (int nf = 0; nf < 4; ++nf)
            bfr[nf] = load_cvt8(bBase + (size_t)nf * 16 * IN_DIM + k);
#pragma unroll
        for (int mf = 0; mf < 4; ++mf)
#pragma unroll
            for (int nf = 0; nf < 4; ++nf)
                acc[mf][nf] = __builtin_amdgcn_mfma_f32_16x16x32_bf16(
                    af[mf], bfr[nf], acc[mf][nf], 0, 0, 0);
    }

    // C/D layout: col = lane&15, row = quad*4 + reg   (row = o here)
#pragma unroll
    for (int mf = 0; mf < 4; ++mf) {
#pragma unroll
        for (int i = 0; i < 4; ++i) {
            const int o    = wm + mf * 16 + quad * 4 + i;
            const float bo = b[o];
#pragma unroll
            for (int nf = 0; nf < 4; ++nf) {
                const int n = n0 + wn + nf * 16 + l16;
                hT[(size_t)o * N_NODES + n] = f2bf(acc[mf][nf][i] + bo);
            }
        }
    }
}

// ---------------------------------------------------------------------------
// GEMM2: out[m][o] = sum_j A_hat[m][j] * hT[o][j]   (M=16384, N=128, K=16384)
// Block: 256 thr = 4 waves (2x2), tile 64(m) x 128(o); wave tile 32x64
// (2x4 frags). Grid = 16384/64 = 256 blocks. A streamed fp32 from HBM
// (1.07 GB total, the roofline), hT (4 MB bf16) L2/LIC-resident.
// ---------------------------------------------------------------------------
__global__ __launch_bounds__(256) void gemm2_ah(
    const float* __restrict__ A, const unsigned short* __restrict__ hT,
    float* __restrict__ out) {
    const int tid  = threadIdx.x;
    const int lane = tid & 63, wid = tid >> 6;
    const int l16  = lane & 15, quad = lane >> 4;
    const int m0   = blockIdx.x * 64;
    const int wm   = (wid >> 1) * 32;
    const int wn   = (wid & 1) * 64;

    f32x4 acc[2][4] = {};

    const float*          aBase = A  + (size_t)(m0 + wm + l16) * N_NODES + quad * 8;
    const unsigned short* bBase = hT + (size_t)(wn + l16) * N_NODES + quad * 8;

#pragma unroll 2
    for (int k = 0; k < N_NODES; k += 32) {
        bf16x8 af[2], bfr[4];
#pragma unroll
        for (int mf = 0; mf < 2; ++mf)
            af[mf] = load_cvt8(aBase + (size_t)mf * 16 * N_NODES + k);
#pragma unroll
        for (int nf = 0; nf < 4; ++nf)
            bfr[nf] = *reinterpret_cast<const bf16x8*>(
                bBase + (size_t)nf * 16 * N_NODES + k);
#pragma unroll
        for (int mf = 0; mf < 2; ++mf)
#pragma unroll
            for (int nf = 0; nf < 4; ++nf)
                acc[mf][nf] = __builtin_amdgcn_mfma_f32_16x16x32_bf16(
                    af[mf], bfr[nf], acc[mf][nf], 0, 0, 0);
    }

#pragma unroll
    for (int mf = 0; mf < 2; ++mf)
#pragma unroll
        for (int i = 0; i < 4; ++i) {
            const int row = m0 + wm + mf * 16 + quad * 4 + i;
#pragma unroll
            for (int nf = 0; nf < 4; ++nf) {
                const int col = wn + nf * 16 + l16;
                out[(size_t)row * OUT_DIM + col] = acc[mf][nf][i];
            }
        }
}

extern "C" void kernel_launch(void* const* d_in, const int* in_sizes, int n_in,
                              void* d_out, int out_size, void* d_ws, size_t ws_size,
                              hipStream_t stream) {
    const float* x     = (const float*)d_in[0];
    const float* A_hat = (const float*)d_in[1];
    const float* W     = (const float*)d_in[2];
    const float* b     = (const float*)d_in[3];
    float* out         = (float*)d_out;
    // hT: 128 x 16384 bf16 = 4 MB in workspace
    unsigned short* hT = (unsigned short*)d_ws;

    gemm1_xw<<<N_NODES / 128, 256, 0, stream>>>(x, W, b, hT);
    gemm2_ah<<<N_NODES / 64, 256, 0, stream>>>(A_hat, hT, out);
}